// Round 6
// baseline (5424.668 us; speedup 1.0000x reference)
//
#include <hip/hip_runtime.h>

typedef unsigned int u32;
typedef unsigned short u16;
typedef __attribute__((ext_vector_type(2))) _Float16 h2v;
typedef __attribute__((ext_vector_type(4))) _Float16 f16x4;
typedef __attribute__((ext_vector_type(4))) float f32x4;

#define BB 32
#define TT 2048
#define CC 256
#define ESZ 256
#define GG 1024   // 4*es

// W2 per gate-column = 128 h2-rows (256 k). Split:
//   rows  0..91  -> VGPRs (92 u32 per thread, 1 col/thread)   [MREG]
//   rows 92..127 -> LDS (9 uint4 chunks, 147 KB)              [NLDS]
// h distribution: rows 0..39 via v_readlane (VALU pipe),
//                 rows 40..127 via same-address ds_read_b128 (LDS pipe).
#define MREG 92
#define NLDS 9
#define XRL 40    // h2-rows distributed via readlane

// ---------------- helpers ----------------
__device__ __forceinline__ float fdot2u(u32 a, u32 b, float c) {
#if __has_builtin(__builtin_amdgcn_fdot2)
  return __builtin_amdgcn_fdot2(__builtin_bit_cast(h2v, a), __builtin_bit_cast(h2v, b), c, false);
#else
  h2v av = __builtin_bit_cast(h2v, a), bv = __builtin_bit_cast(h2v, b);
  return c + (float)av[0] * (float)bv[0] + (float)av[1] * (float)bv[1];
#endif
}

__device__ __forceinline__ float sigm_f(float x) {
  float e = __builtin_amdgcn_exp2f(x * -1.442695041f);
  return __builtin_amdgcn_rcpf(1.0f + e);
}
__device__ __forceinline__ float tanh_f(float x) {
  float e = __builtin_amdgcn_exp2f(x * 2.885390082f);  // exp(2x)
  return 1.0f - 2.0f * __builtin_amdgcn_rcpf(e + 1.0f);
}

// ---------------- kernel 0: pack W2 (f32 [256][1024] -> h2 rows [128][1024]) ----------------
__global__ void k_pack_w2(const float* __restrict__ W2, u32* __restrict__ W2p) {
  int gid = blockIdx.x * 256 + threadIdx.x;   // m = gid>>10, j = gid&1023
  int m = gid >> 10, j = gid & 1023;
  _Float16 lo = (_Float16)W2[(size_t)(2 * m) * GG + j];
  _Float16 hi = (_Float16)W2[(size_t)(2 * m + 1) * GG + j];
  W2p[gid] = (u32)__builtin_bit_cast(u16, lo) | ((u32)__builtin_bit_cast(u16, hi) << 16);
}

// ---------------- kernel 1: pre = x@W1 + b1 + b2  (f16 MFMA, out f16 [B*T][1024]) ----------------
__global__ __launch_bounds__(256, 2) void k_pre_gemm(
    const float* __restrict__ x, const float* __restrict__ W1,
    const float* __restrict__ b1, const float* __restrict__ b2,
    _Float16* __restrict__ pre) {
  __shared__ __attribute__((aligned(16))) _Float16 Al[128 * 36];
  __shared__ __attribute__((aligned(16))) _Float16 Bl[64 * 36];
  const int tid = threadIdx.x;
  const int lane = tid & 63, wv = tid >> 6;
  const int wr = wv >> 1, wc = wv & 1;
  const int rowBase = blockIdx.x * 128;
  const int colBase = blockIdx.y * 64;

  f32x4 acc[4][2];
#pragma unroll
  for (int mi = 0; mi < 4; ++mi)
#pragma unroll
    for (int ni = 0; ni < 2; ++ni) acc[mi][ni] = (f32x4){0.f, 0.f, 0.f, 0.f};

  for (int k0 = 0; k0 < 256; k0 += 32) {
#pragma unroll
    for (int i = 0; i < 4; ++i) {
      int fidx = tid + 256 * i;
      int row = fidx >> 3, kc = (fidx & 7) * 4;
      const float4 v = *(const float4*)(x + (size_t)(rowBase + row) * 256 + k0 + kc);
      f16x4 hv = { (_Float16)v.x, (_Float16)v.y, (_Float16)v.z, (_Float16)v.w };
      *(f16x4*)&Al[row * 36 + kc] = hv;
    }
#pragma unroll
    for (int i = 0; i < 8; ++i) {
      int idx = tid + 256 * i;
      int k = idx >> 6, n = idx & 63;
      Bl[n * 36 + k] = (_Float16)W1[(size_t)(k0 + k) * GG + colBase + n];
    }
    __syncthreads();

#pragma unroll
    for (int kk = 0; kk < 2; ++kk) {
      int ka = (lane >> 4) * 4 + kk * 16;
      f16x4 af[4], bf[2];
#pragma unroll
      for (int mi = 0; mi < 4; ++mi)
        af[mi] = *(const f16x4*)&Al[(wr * 64 + mi * 16 + (lane & 15)) * 36 + ka];
#pragma unroll
      for (int ni = 0; ni < 2; ++ni)
        bf[ni] = *(const f16x4*)&Bl[(wc * 32 + ni * 16 + (lane & 15)) * 36 + ka];
#pragma unroll
      for (int mi = 0; mi < 4; ++mi)
#pragma unroll
        for (int ni = 0; ni < 2; ++ni)
          acc[mi][ni] = __builtin_amdgcn_mfma_f32_16x16x16f16(af[mi], bf[ni], acc[mi][ni], 0, 0, 0);
    }
    __syncthreads();
  }

#pragma unroll
  for (int ni = 0; ni < 2; ++ni) {
    int col = colBase + wc * 32 + ni * 16 + (lane & 15);
    float bias = b1[col] + b2[col];
#pragma unroll
    for (int mi = 0; mi < 4; ++mi) {
      int r0 = rowBase + wr * 64 + mi * 16 + (lane >> 4) * 4;
#pragma unroll
      for (int rr = 0; rr < 4; ++rr)
        pre[(size_t)(r0 + rr) * GG + col] = (_Float16)(acc[mi][ni][rr] + bias);
    }
  }
}

// ---------------- kernel 2: the recurrence ----------------
// 32 blocks (one per batch), 1024 threads (16 waves, EXACTLY 4/SIMD -> 128 VGPRs).
// Thread t owns gate column t. NO per-step L2 traffic: W2 entirely VGPR+LDS.
__global__ __launch_bounds__(1024)
__attribute__((amdgpu_waves_per_eu(4, 4)))
void k_lstm_rec(
    const _Float16* __restrict__ pre, const u32* __restrict__ W2p,
    const float* __restrict__ h0, const float* __restrict__ c0,
    float* __restrict__ out1, float* __restrict__ out2,
    float* __restrict__ hN, float* __restrict__ cN) {
  extern __shared__ __attribute__((aligned(16))) char smem[];
  uint4* W2Lw = (uint4*)smem;                                   // NLDS*1024 uint4 = 147456 B
  const uint4* W2L = (const uint4*)smem;
  _Float16* hbuf = (_Float16*)(smem + NLDS * 1024 * 16);        // 256 f16 = 512 B
  const u32* hrow = (const u32*)(smem + NLDS * 1024 * 16);      // h as 128 h2
  const uint4* hb4 = (const uint4*)(smem + NLDS * 1024 * 16);   // h as 32 uint4
  float* exch = (float*)(smem + NLDS * 1024 * 16 + 512);        // [4][260] f32

  const int t = threadIdx.x;     // gate column 0..1023
  const int b = blockIdx.x;
  const int j = t & 255;         // es index
  const int gate = t >> 8;       // 0:f 1:i 2:o 3:ch
  const int lane = t & 63;

  // register-resident W2 rows 0..MREG-1 for this column
  u32 w[MREG];
#pragma unroll
  for (int m = 0; m < MREG; ++m) w[m] = W2p[m * GG + t];
#pragma unroll
  for (int m = 0; m < MREG; ++m) asm volatile("" : "+v"(w[m]));  // pin

  // LDS-resident rows MREG..127: chunk c holds rows MREG+4c..MREG+4c+3
#pragma unroll
  for (int c = 0; c < NLDS; ++c) {
    int m0 = MREG + 4 * c;
    uint4 v;
    v.x = W2p[(m0 + 0) * GG + t];
    v.y = W2p[(m0 + 1) * GG + t];
    v.z = W2p[(m0 + 2) * GG + t];
    v.w = W2p[(m0 + 3) * GG + t];
    W2Lw[c * 1024 + t] = v;
  }

  float creg = 0.f, hlast = 0.f;
  if (t < ESZ) {
    hbuf[t] = (_Float16)h0[b * ESZ + t];
    creg = c0[b * ESZ + t];
  }
  __syncthreads();

  const _Float16* preB = pre + (size_t)b * TT * GG;
  _Float16 q = preB[t];

  for (int s = 0; s < TT; ++s) {
    u32 hv0 = hrow[lane];        // per-lane b32: rows 0..63 spread over lanes
    float a0 = 0.f, a1 = 0.f;

    // part 1: rows 0..XRL-1 via readlane (VALU pipe)
#pragma unroll
    for (int m = 0; m < XRL; ++m) {
      u32 hm = (u32)__builtin_amdgcn_readlane((int)hv0, m);
      if (m & 1) a1 = fdot2u(hm, w[m], a1);
      else       a0 = fdot2u(hm, w[m], a0);
    }
    // part 2: rows XRL..MREG-1 via broadcast b128 (LDS pipe), weights in VGPR
#pragma unroll
    for (int c = 0; c < (MREG - XRL) / 4; ++c) {
      uint4 hh = hb4[XRL / 4 + c];           // same addr across wave -> broadcast
      a0 = fdot2u(hh.x, w[XRL + 4 * c + 0], a0);
      a1 = fdot2u(hh.y, w[XRL + 4 * c + 1], a1);
      a0 = fdot2u(hh.z, w[XRL + 4 * c + 2], a0);
      a1 = fdot2u(hh.w, w[XRL + 4 * c + 3], a1);
    }
    // part 3: rows MREG..127, weights from LDS (per-lane b128, stride-16 no-conflict)
#pragma unroll
    for (int c = 0; c < NLDS; ++c) {
      uint4 hh = hb4[MREG / 4 + c];
      uint4 wv = W2L[c * 1024 + t];
      a0 = fdot2u(hh.x, wv.x, a0);
      a1 = fdot2u(hh.y, wv.y, a1);
      a0 = fdot2u(hh.z, wv.z, a0);
      a1 = fdot2u(hh.w, wv.w, a1);
    }

    float v = (float)q + a0 + a1;
    if (s + 1 < TT) q = preB[(size_t)(s + 1) * GG + t];  // prefetch next pre

    float g = (gate == 3) ? tanh_f(v) : sigm_f(v);       // wave-uniform branch
    exch[gate * 260 + j] = g;

    // B1: exch visible; LDS-only drain (global prefetch/stores stay in flight)
    asm volatile("s_waitcnt lgkmcnt(0)" ::: "memory");
    __builtin_amdgcn_s_barrier();

    if (t < ESZ) {
      float fg = exch[0 * 260 + t];
      float ig = exch[1 * 260 + t];
      float og = exch[2 * 260 + t];
      float ch = exch[3 * 260 + t];
      creg = fg * creg + ig * ch;
      float hv = og * tanh_f(creg);
      hlast = hv;
      out1[(size_t)b * TT * ESZ + (size_t)s * ESZ + t] = hv;   // [B, T*es]
      out2[(size_t)s * (BB * ESZ) + b * ESZ + t] = hv;         // [T, B, es]
      hbuf[t] = (_Float16)hv;
    }

    // B2: next step's h visible
    asm volatile("s_waitcnt lgkmcnt(0)" ::: "memory");
    __builtin_amdgcn_s_barrier();
  }

  if (t < ESZ) {
    hN[b * ESZ + t] = hlast;
    cN[b * ESZ + t] = creg;
  }
}

// ---------------- launch ----------------
extern "C" void kernel_launch(void* const* d_in, const int* in_sizes, int n_in,
                              void* d_out, int out_size, void* d_ws, size_t ws_size,
                              hipStream_t stream) {
  const float* x  = (const float*)d_in[0];
  const float* h0 = (const float*)d_in[1];
  const float* c0 = (const float*)d_in[2];
  const float* W1 = (const float*)d_in[3];
  const float* W2 = (const float*)d_in[4];
  const float* b1 = (const float*)d_in[5];
  const float* b2 = (const float*)d_in[6];

  float* out1 = (float*)d_out;
  float* out2 = out1 + (size_t)BB * TT * ESZ;
  float* hN   = out2 + (size_t)BB * TT * ESZ;
  float* cN   = hN + BB * ESZ;

  _Float16* pre = (_Float16*)d_ws;                                  // 128 MB
  u32* W2p = (u32*)((char*)d_ws + (size_t)BB * TT * GG * 2);        // 512 KB

  k_pack_w2<<<512, 256, 0, stream>>>(W2, W2p);
  k_pre_gemm<<<dim3(512, 16), 256, 0, stream>>>(x, W1, b1, b2, pre);

  const int ldsBytes = NLDS * 1024 * 16 + 512 + 4 * 260 * 4;  // 147456 + 512 + 4160
  hipFuncSetAttribute((const void*)k_lstm_rec, hipFuncAttributeMaxDynamicSharedMemorySize, ldsBytes);
  k_lstm_rec<<<BB, 1024, ldsBytes, stream>>>(pre, W2p, h0, c0, out1, out2, hN, cN);
}